// Round 2
// baseline (16884.727 us; speedup 1.0000x reference)
//
#include <hip/hip_runtime.h>
#include <hip/hip_bf16.h>

#define DEV __device__ __forceinline__

namespace {
constexpr int T_ = 16;
constexpr int C_ = 64;
constexpr int H_ = 128;
constexpr int W_ = 128;
constexpr int HW_ = H_ * W_;            // 16384
constexpr long CHW_ = (long)C_ * HW_;   // 1,048,576 floats per (n,t) plane
}

struct Bil { int o00, o01, o10, o11; float w00, w01, w10, w11; };

DEV Bil make_bil(float gx, float gy) {
  float x0f = floorf(gx), y0f = floorf(gy);
  float wx = gx - x0f, wy = gy - y0f;
  int x0 = (int)x0f, y0 = (int)y0f;
  int x1 = x0 + 1, y1 = y0 + 1;
  bool vx0 = (x0 >= 0) && (x0 < W_), vx1 = (x1 >= 0) && (x1 < W_);
  bool vy0 = (y0 >= 0) && (y0 < H_), vy1 = (y1 >= 0) && (y1 < H_);
  int cx0 = min(max(x0, 0), W_ - 1), cx1 = min(max(x1, 0), W_ - 1);
  int cy0 = min(max(y0, 0), H_ - 1), cy1 = min(max(y1, 0), H_ - 1);
  Bil b;
  b.o00 = cy0 * W_ + cx0; b.o01 = cy0 * W_ + cx1;
  b.o10 = cy1 * W_ + cx0; b.o11 = cy1 * W_ + cx1;
  b.w00 = (vx0 && vy0) ? (1.f - wx) * (1.f - wy) : 0.f;
  b.w01 = (vx1 && vy0) ? wx * (1.f - wy) : 0.f;
  b.w10 = (vx0 && vy1) ? (1.f - wx) * wy : 0.f;
  b.w11 = (vx1 && vy1) ? wx * wy : 0.f;
  return b;
}

// Kernel 1: flow-warp (a2, a1) + concat x + 1x1 conv (192->64), all fp32.
// grid = 256 blocks x 256 threads; thread = (n, co-half, pixel).
// v3: R1 analysis showed this kernel is LDS-INSTRUCTION bound: 32x
// ds_read_b32 per k (6144/thread, ~59us of LDS issue per CU). Fix: read wl
// as float4 (8x ds_read_b128 per k) and batch gathers 4-ci at a time for
// ILP. Per-acc k-order unchanged -> bit-identical output.
__global__ __launch_bounds__(256) void warp_fc_k(
    const float* __restrict__ flows,    // (N,T,2,HW)
    const float* __restrict__ xfeats,   // pristine feats base (x_t source)
    const float* __restrict__ y1p, long y1s,   // y1 planes, n-stride (floats)
    const float* __restrict__ y2p, long y2s,   // y2 planes
    const float* __restrict__ Wfc, const float* __restrict__ bfc,
    int f1t, int f2t, int t,
    float* __restrict__ ifp, long ifs) {       // infeat out, n-stride
  __shared__ __align__(16) float wl[192 * 64];   // k-major: wl[k*64+co]
  const int tid = threadIdx.x;
  for (int i = tid; i < 192 * 64; i += 256) {
    int k = i >> 6, co = i & 63;
    wl[i] = Wfc[co * 192 + k];
  }
  __syncthreads();

  const int n    = blockIdx.x >> 7;          // 0..1
  const int half = (blockIdx.x >> 6) & 1;    // co-half 0..1
  const int p    = ((blockIdx.x & 63) << 8) + tid;   // 0..16383
  const int py = p >> 7, px = p & (W_ - 1);

  float f1x = 0.f, f1y = 0.f;
  if (f1t >= 0) {
    const float* fp = flows + (long)((n * T_ + f1t) * 2) * HW_;
    f1x = fp[p];
    f1y = fp[HW_ + p];
  }
  Bil b1 = make_bil((float)px + f1x, (float)py + f1y);

  float f2cx = f1x, f2cy = f1y;   // warp of zero field is zero
  if (f2t >= 0) {
    const float* f2p = flows + (long)((n * T_ + f2t) * 2) * HW_;
    f2cx += b1.w00 * f2p[b1.o00] + b1.w01 * f2p[b1.o01] +
            b1.w10 * f2p[b1.o10] + b1.w11 * f2p[b1.o11];
    const float* f2q = f2p + HW_;
    f2cy += b1.w00 * f2q[b1.o00] + b1.w01 * f2q[b1.o01] +
            b1.w10 * f2q[b1.o10] + b1.w11 * f2q[b1.o11];
  }
  Bil b2 = make_bil((float)px + f2cx, (float)py + f2cy);

  float acc[32];
  #pragma unroll
  for (int i = 0; i < 32; i++) acc[i] = bfc[half * 32 + i];

  // k = 0..63 : a2 = warp(y2, f2c)
  const float* y2b = y2p + (long)n * y2s;
  for (int c0 = 0; c0 < 64; c0 += 4) {
    float v[4];
    #pragma unroll
    for (int u = 0; u < 4; ++u) {
      const float* pl = y2b + (long)(c0 + u) * HW_;
      v[u] = b2.w00 * pl[b2.o00] + b2.w01 * pl[b2.o01] +
             b2.w10 * pl[b2.o10] + b2.w11 * pl[b2.o11];
    }
    #pragma unroll
    for (int u = 0; u < 4; ++u) {
      const float4* wr = (const float4*)(wl + (c0 + u) * 64 + half * 32);
      #pragma unroll
      for (int i8 = 0; i8 < 8; ++i8) {
        float4 ww = wr[i8];
        acc[i8 * 4 + 0] += ww.x * v[u];
        acc[i8 * 4 + 1] += ww.y * v[u];
        acc[i8 * 4 + 2] += ww.z * v[u];
        acc[i8 * 4 + 3] += ww.w * v[u];
      }
    }
  }
  // k = 64..127 : a1 = warp(y1, f1)
  const float* y1b = y1p + (long)n * y1s;
  for (int c0 = 0; c0 < 64; c0 += 4) {
    float v[4];
    #pragma unroll
    for (int u = 0; u < 4; ++u) {
      const float* pl = y1b + (long)(c0 + u) * HW_;
      v[u] = b1.w00 * pl[b1.o00] + b1.w01 * pl[b1.o01] +
             b1.w10 * pl[b1.o10] + b1.w11 * pl[b1.o11];
    }
    #pragma unroll
    for (int u = 0; u < 4; ++u) {
      const float4* wr = (const float4*)(wl + (64 + c0 + u) * 64 + half * 32);
      #pragma unroll
      for (int i8 = 0; i8 < 8; ++i8) {
        float4 ww = wr[i8];
        acc[i8 * 4 + 0] += ww.x * v[u];
        acc[i8 * 4 + 1] += ww.y * v[u];
        acc[i8 * 4 + 2] += ww.z * v[u];
        acc[i8 * 4 + 3] += ww.w * v[u];
      }
    }
  }
  // k = 128..191 : x = feats[:, t]
  const float* xb = xfeats + (long)(n * T_ + t) * CHW_ + p;
  for (int c0 = 0; c0 < 64; c0 += 4) {
    float v[4];
    #pragma unroll
    for (int u = 0; u < 4; ++u) v[u] = xb[(long)(c0 + u) * HW_];
    #pragma unroll
    for (int u = 0; u < 4; ++u) {
      const float4* wr = (const float4*)(wl + (128 + c0 + u) * 64 + half * 32);
      #pragma unroll
      for (int i8 = 0; i8 < 8; ++i8) {
        float4 ww = wr[i8];
        acc[i8 * 4 + 0] += ww.x * v[u];
        acc[i8 * 4 + 1] += ww.y * v[u];
        acc[i8 * 4 + 2] += ww.z * v[u];
        acc[i8 * 4 + 3] += ww.w * v[u];
      }
    }
  }

  float* o = ifp + (long)n * ifs + p;
  #pragma unroll
  for (int i = 0; i < 32; i++) o[(long)(half * 32 + i) * HW_] = acc[i];
}

DEV float f4c(const float4& v, int k) {
  return k == 0 ? v.x : k == 1 ? v.y : k == 2 ? v.z : v.w;
}

// 3x3 SAME conv 64->64, fp32. v3:
//   R1 post-mortem: v2 (119us, VALUBusy 22%, VGPR 52) was LATENCY-bound, not
//   conflict-bound — per-ci serial chain {18 scalar weight VMEM -> wait ->
//   ds_read -> wait -> FMA}, no pipelining (low VGPR = compiler kept nothing
//   in flight), 8 barrier-locked waves/CU.
//   Fix (keeps v2's conflict-free TS=24 tile + 2co/thread mapping; FMA order
//   per output unchanged -> bit-identical):
//     * double-buffered LDS tile, ONE barrier per 4-ci round;
//     * staging global->reg prefetched one round ahead (T14 issue-early /
//       write-late split): HBM latency hides under the 576-FMA round;
//     * weights as 9 aligned float4 per co per round (vs 72 scalar loads),
//       double-buffered one round ahead;
//     * launch_bounds(256,2): allow ~230 VGPR at the same 8 waves/CU.
//   Expected floor: LDS-read bound, 8 waves x 32 b128 x 12cyc = 3072 cyc per
//   round x 16 rounds ~= 23 us/dispatch.
template <int MODE>
__global__ __launch_bounds__(256, 2) void conv3_k(
    const float* __restrict__ in, long ins,       // input planes, n-stride
    const float* __restrict__ Wt,                 // (64,64,3,3)
    const float* __restrict__ bias,
    const float* __restrict__ xfeats, int t,      // residual source (MODE 1)
    float* __restrict__ outf, long outs) {        // fp32 out planes, n-stride
  constexpr int TS = 24;         // padded tile row stride (floats)
  constexpr int PL = 18 * TS;    // 432 floats per ci plane
  constexpr int HB = 4 * PL;     // 1728 floats per buffer (4 ci)
  __shared__ __align__(16) float tile[2 * HB];    // 13.8 KiB

  const int tilex = blockIdx.x, tiley = blockIdx.y;
  const int n = blockIdx.z >> 2, cog = blockIdx.z & 3;
  const int tid = threadIdx.x;
  const int colane = tid & 7;        // 0..7
  const int patch  = tid >> 3;       // 0..31
  const int prr = patch >> 2;        // 0..7  (2-row strips)
  const int pcc = patch & 3;         // 0..3  (4-col strips)
  const int co0 = cog * 16 + colane; // thread's channels: co0 and co0+8

  const float* inn = in + (long)n * ins;
  const int gy0 = tiley * 16 - 1, gx0 = tilex * 16 - 1;

  // ---- staging slots: 4 planes x 18x18 = 1296 elems over 256 threads ----
  int soff[6]; int slds[6]; bool sval[6]; bool sact[6];
  #pragma unroll
  for (int s = 0; s < 6; ++s) {
    int idx = tid + s * 256;
    sact[s] = idx < 1296;
    int idc = sact[s] ? idx : 0;
    int cc = idc / 324; int rem = idc - cc * 324;
    int r = rem / 18;   int c = rem - r * 18;
    int gy = gy0 + r, gx = gx0 + c;
    bool inb = (gy >= 0) && (gy < H_) && (gx >= 0) && (gx < W_);
    sval[s] = sact[s] && inb;
    soff[s] = cc * HW_ + (inb ? (gy * W_ + gx) : 0);
    slds[s] = cc * PL + r * TS + c;
  }

  const float* wp0 = Wt + (long)co0 * 576;        // 64 ci * 9 floats
  const float* wp1 = Wt + (long)(co0 + 8) * 576;

  float4 wA0[9], wA1[9], wB0[9], wB1[9];
  #pragma unroll
  for (int j = 0; j < 9; ++j) {                   // weights for round 0 (ci 0..3)
    wA0[j] = ((const float4*)wp0)[j];
    wA1[j] = ((const float4*)wp1)[j];
  }

  float sreg[6];
  #pragma unroll
  for (int s = 0; s < 6; ++s) sreg[s] = sval[s] ? inn[soff[s]] : 0.f;

  float acc[2][2][4];
  #pragma unroll
  for (int q = 0; q < 2; q++)
    #pragma unroll
    for (int i = 0; i < 2; i++)
      #pragma unroll
      for (int j = 0; j < 4; j++) acc[q][i][j] = 0.f;

  // prologue: write round 0 into buffer 0
  #pragma unroll
  for (int s = 0; s < 6; ++s) if (sact[s]) tile[slds[s]] = sreg[s];
  __syncthreads();

  // one cc-step: 8x ds_read_b128 + 144 FMA. CC is a literal -> all weight
  // component extraction is compile-time (f4c folds).
#define CCSTEP(TB, CC, WC0, WC1)                                              \
  {                                                                           \
    float vv[4][8];                                                           \
    _Pragma("unroll")                                                         \
    for (int r = 0; r < 4; ++r) {                                             \
      const float* tp = (TB) + (CC) * PL + (prr * 2 + r) * TS + pcc * 4;      \
      float4 va = *(const float4*)tp;                                         \
      float4 vb = *(const float4*)(tp + 4);                                   \
      vv[r][0] = va.x; vv[r][1] = va.y; vv[r][2] = va.z; vv[r][3] = va.w;     \
      vv[r][4] = vb.x; vv[r][5] = vb.y; vv[r][6] = vb.z; vv[r][7] = vb.w;     \
    }                                                                         \
    _Pragma("unroll")                                                         \
    for (int oy = 0; oy < 2; ++oy) {                                          \
      _Pragma("unroll")                                                       \
      for (int ky = 0; ky < 3; ++ky) {                                        \
        _Pragma("unroll")                                                     \
        for (int kx = 0; kx < 3; ++kx) {                                      \
          const int jj = (CC) * 9 + ky * 3 + kx;                              \
          float w0 = f4c(WC0[jj >> 2], jj & 3);                               \
          float w1 = f4c(WC1[jj >> 2], jj & 3);                               \
          _Pragma("unroll")                                                   \
          for (int ox = 0; ox < 4; ++ox) {                                    \
            float x = vv[oy + ky][ox + kx];                                   \
            acc[0][oy][ox] += w0 * x;                                         \
            acc[1][oy][ox] += w1 * x;                                         \
          }                                                                   \
        }                                                                     \
      }                                                                       \
    }                                                                         \
  }

  // one round: prefetch next round's staging+weights, compute 4 ci from
  // buf BUF, ds_write next round into buf 1-BUF, single barrier.
#define ROUND(CB, BUF, WC0, WC1, WN0, WN1)                                    \
  {                                                                           \
    const bool more = (CB) + 4 < 64;                                          \
    if (more) {                                                               \
      const float* nb = inn + (long)((CB) + 4) * HW_;                         \
      _Pragma("unroll")                                                       \
      for (int s = 0; s < 6; ++s) sreg[s] = sval[s] ? nb[soff[s]] : 0.f;      \
      const float4* q0 = (const float4*)(wp0 + ((CB) + 4) * 9);               \
      const float4* q1 = (const float4*)(wp1 + ((CB) + 4) * 9);               \
      _Pragma("unroll")                                                       \
      for (int j = 0; j < 9; ++j) { WN0[j] = q0[j]; WN1[j] = q1[j]; }         \
    }                                                                         \
    const float* tb = tile + (BUF) * HB;                                      \
    CCSTEP(tb, 0, WC0, WC1)                                                   \
    CCSTEP(tb, 1, WC0, WC1)                                                   \
    CCSTEP(tb, 2, WC0, WC1)                                                   \
    CCSTEP(tb, 3, WC0, WC1)                                                   \
    if (more) {                                                               \
      float* db = tile + (1 - (BUF)) * HB;                                    \
      _Pragma("unroll")                                                       \
      for (int s = 0; s < 6; ++s) if (sact[s]) db[slds[s]] = sreg[s];         \
    }                                                                         \
    __syncthreads();                                                          \
  }

  for (int ii = 0; ii < 8; ++ii) {     // 2 rounds per iter, alternating bufs
    const int cb = ii * 8;
    ROUND(cb,     0, wA0, wA1, wB0, wB1)
    ROUND(cb + 4, 1, wB0, wB1, wA0, wA1)
  }
#undef ROUND
#undef CCSTEP

  // ---- epilogue: bias (+leaky | +residual), float4 stores ----
  const int py0 = tiley * 16 + prr * 2, px0 = tilex * 16 + pcc * 4;
  #pragma unroll
  for (int q = 0; q < 2; q++) {
    const int co = co0 + q * 8;
    const float bs = bias[co];
    float* ob = outf + (long)n * outs + (long)co * HW_;
    const float* xb = (MODE == 1)
        ? xfeats + (long)(n * T_ + t) * CHW_ + (long)co * HW_ : nullptr;
    #pragma unroll
    for (int oy = 0; oy < 2; oy++) {
      const long p = (long)(py0 + oy) * W_ + px0;
      float4 r;
      r.x = acc[q][oy][0] + bs;
      r.y = acc[q][oy][1] + bs;
      r.z = acc[q][oy][2] + bs;
      r.w = acc[q][oy][3] + bs;
      if (MODE == 0) {
        r.x = (r.x > 0.f) ? r.x : 0.1f * r.x;
        r.y = (r.y > 0.f) ? r.y : 0.1f * r.y;
        r.z = (r.z > 0.f) ? r.z : 0.1f * r.z;
        r.w = (r.w > 0.f) ? r.w : 0.1f * r.w;
      } else {
        float4 xres = *reinterpret_cast<const float4*>(&xb[p]);
        r.x += xres.x; r.y += xres.y; r.z += xres.z; r.w += xres.w;
      }
      *reinterpret_cast<float4*>(&ob[p]) = r;
    }
  }
}

extern "C" void kernel_launch(void* const* d_in, const int* in_sizes, int n_in,
                              void* d_out, int out_size, void* d_ws, size_t ws_size,
                              hipStream_t stream) {
  // Inputs fp32 AND output fp32 (reference returns jnp.float32; the test's
  // "(bf16, ...)" label is a hardcoded string).
  //
  // d_out planes (n,t) are the exact fp32 recurrent state: written at step t,
  // read as y1/y2 at steps t+1/t+2 (feats plane 0 for t<2). Scratch (infeat,
  // h1) -> d_ws if >=16 MiB, else dead feats/d_out planes (restore-per-launch
  // semantics make feats planes reusable once consumed).
  float* fmut = (float*)d_in[0];              // feats (2,16,64,128,128)
  const float* flows = (const float*)d_in[1]; // (2,16,2,128,128)
  const float* Wfc   = (const float*)d_in[2]; // (64,192)
  const float* bfc   = (const float*)d_in[3];
  const float* W1    = (const float*)d_in[4]; // (64,64,3,3)
  const float* b1v   = (const float*)d_in[5];
  const float* W2    = (const float*)d_in[6];
  const float* b2v   = (const float*)d_in[7];
  float* outF = (float*)d_out;                // (2,16,64,128,128) fp32

  const long FS = (long)T_ * CHW_;            // n-stride of feats/out (floats)
  float* ws = (float*)d_ws;
  const bool use_ws = ws_size >= (size_t)4 * CHW_ * sizeof(float);  // 16 MiB

  dim3 g3(8, 8, 8);
  for (int t = 0; t < T_; t++) {
    // ---- state sources (n-stride FS for both feats and out) ----
    const float* y1p = (t >= 1) ? outF + (long)(t - 1) * CHW_ : fmut;
    const float* y2p = (t >= 2) ? outF + (long)(t - 2) * CHW_ : fmut;

    // ---- scratch: infeat and h1 ----
    float *ifp, *h1p;
    long ifs, h1s;
    if (use_ws) {
      ifp = ws;                 ifs = CHW_;   // (N,C,H,W), 8 MiB
      h1p = ws + 2 * CHW_;      h1s = CHW_;   // 8 MiB
    } else {
      if (t == 0)      { ifp = outF + (long)14 * CHW_; ifs = FS; }
      else if (t == 1) { ifp = outF + (long)15 * CHW_; ifs = FS; }
      else             { ifp = fmut + (long)(t - 1) * CHW_; ifs = FS; }
      if (t == 0)      { h1p = outF + (long)15 * CHW_; h1s = FS; }
      else             { h1p = fmut; h1s = FS; }   // feats plane 0, dead for t>=1
    }

    warp_fc_k<<<256, 256, 0, stream>>>(
        flows, fmut, y1p, FS, y2p, FS, Wfc, bfc, t - 1, t - 2, t, ifp, ifs);
    conv3_k<0><<<g3, 256, 0, stream>>>(ifp, ifs, W1, b1v, nullptr, 0, h1p, h1s);
    conv3_k<1><<<g3, 256, 0, stream>>>(h1p, h1s, W2, b2v, fmut, t,
                                       outF + (long)t * CHW_, FS);
  }
}

// Round 3
// 3922.136 us; speedup vs baseline: 4.3050x; 4.3050x over previous
//
#include <hip/hip_runtime.h>
#include <hip/hip_bf16.h>

#define DEV __device__ __forceinline__

namespace {
constexpr int T_ = 16;
constexpr int C_ = 64;
constexpr int H_ = 128;
constexpr int W_ = 128;
constexpr int HW_ = H_ * W_;            // 16384
constexpr long CHW_ = (long)C_ * HW_;   // 1,048,576 floats per (n,t) plane
}

struct Bil { int o00, o01, o10, o11; float w00, w01, w10, w11; };

DEV Bil make_bil(float gx, float gy) {
  float x0f = floorf(gx), y0f = floorf(gy);
  float wx = gx - x0f, wy = gy - y0f;
  int x0 = (int)x0f, y0 = (int)y0f;
  int x1 = x0 + 1, y1 = y0 + 1;
  bool vx0 = (x0 >= 0) && (x0 < W_), vx1 = (x1 >= 0) && (x1 < W_);
  bool vy0 = (y0 >= 0) && (y0 < H_), vy1 = (y1 >= 0) && (y1 < H_);
  int cx0 = min(max(x0, 0), W_ - 1), cx1 = min(max(x1, 0), W_ - 1);
  int cy0 = min(max(y0, 0), H_ - 1), cy1 = min(max(y1, 0), H_ - 1);
  Bil b;
  b.o00 = cy0 * W_ + cx0; b.o01 = cy0 * W_ + cx1;
  b.o10 = cy1 * W_ + cx0; b.o11 = cy1 * W_ + cx1;
  b.w00 = (vx0 && vy0) ? (1.f - wx) * (1.f - wy) : 0.f;
  b.w01 = (vx1 && vy0) ? wx * (1.f - wy) : 0.f;
  b.w10 = (vx0 && vy1) ? (1.f - wx) * wy : 0.f;
  b.w11 = (vx1 && vy1) ? wx * wy : 0.f;
  return b;
}

// Kernel 1: flow-warp (a2, a1) + concat x + 1x1 conv (192->64), all fp32.
// grid = 256 blocks x 256 threads; thread = (n, co-half, pixel).
// (v3 form: float4 wl reads. Likely gather/TA-bound; revisit with counters.)
__global__ __launch_bounds__(256) void warp_fc_k(
    const float* __restrict__ flows,    // (N,T,2,HW)
    const float* __restrict__ xfeats,   // pristine feats base (x_t source)
    const float* __restrict__ y1p, long y1s,   // y1 planes, n-stride (floats)
    const float* __restrict__ y2p, long y2s,   // y2 planes
    const float* __restrict__ Wfc, const float* __restrict__ bfc,
    int f1t, int f2t, int t,
    float* __restrict__ ifp, long ifs) {       // infeat out, n-stride
  __shared__ __align__(16) float wl[192 * 64];   // k-major: wl[k*64+co]
  const int tid = threadIdx.x;
  for (int i = tid; i < 192 * 64; i += 256) {
    int k = i >> 6, co = i & 63;
    wl[i] = Wfc[co * 192 + k];
  }
  __syncthreads();

  const int n    = blockIdx.x >> 7;          // 0..1
  const int half = (blockIdx.x >> 6) & 1;    // co-half 0..1
  const int p    = ((blockIdx.x & 63) << 8) + tid;   // 0..16383
  const int py = p >> 7, px = p & (W_ - 1);

  float f1x = 0.f, f1y = 0.f;
  if (f1t >= 0) {
    const float* fp = flows + (long)((n * T_ + f1t) * 2) * HW_;
    f1x = fp[p];
    f1y = fp[HW_ + p];
  }
  Bil b1 = make_bil((float)px + f1x, (float)py + f1y);

  float f2cx = f1x, f2cy = f1y;   // warp of zero field is zero
  if (f2t >= 0) {
    const float* f2p = flows + (long)((n * T_ + f2t) * 2) * HW_;
    f2cx += b1.w00 * f2p[b1.o00] + b1.w01 * f2p[b1.o01] +
            b1.w10 * f2p[b1.o10] + b1.w11 * f2p[b1.o11];
    const float* f2q = f2p + HW_;
    f2cy += b1.w00 * f2q[b1.o00] + b1.w01 * f2q[b1.o01] +
            b1.w10 * f2q[b1.o10] + b1.w11 * f2q[b1.o11];
  }
  Bil b2 = make_bil((float)px + f2cx, (float)py + f2cy);

  float acc[32];
  #pragma unroll
  for (int i = 0; i < 32; i++) acc[i] = bfc[half * 32 + i];

  // k = 0..63 : a2 = warp(y2, f2c)
  const float* y2b = y2p + (long)n * y2s;
  for (int c0 = 0; c0 < 64; c0 += 4) {
    float v[4];
    #pragma unroll
    for (int u = 0; u < 4; ++u) {
      const float* pl = y2b + (long)(c0 + u) * HW_;
      v[u] = b2.w00 * pl[b2.o00] + b2.w01 * pl[b2.o01] +
             b2.w10 * pl[b2.o10] + b2.w11 * pl[b2.o11];
    }
    #pragma unroll
    for (int u = 0; u < 4; ++u) {
      const float4* wr = (const float4*)(wl + (c0 + u) * 64 + half * 32);
      #pragma unroll
      for (int i8 = 0; i8 < 8; ++i8) {
        float4 ww = wr[i8];
        acc[i8 * 4 + 0] += ww.x * v[u];
        acc[i8 * 4 + 1] += ww.y * v[u];
        acc[i8 * 4 + 2] += ww.z * v[u];
        acc[i8 * 4 + 3] += ww.w * v[u];
      }
    }
  }
  // k = 64..127 : a1 = warp(y1, f1)
  const float* y1b = y1p + (long)n * y1s;
  for (int c0 = 0; c0 < 64; c0 += 4) {
    float v[4];
    #pragma unroll
    for (int u = 0; u < 4; ++u) {
      const float* pl = y1b + (long)(c0 + u) * HW_;
      v[u] = b1.w00 * pl[b1.o00] + b1.w01 * pl[b1.o01] +
             b1.w10 * pl[b1.o10] + b1.w11 * pl[b1.o11];
    }
    #pragma unroll
    for (int u = 0; u < 4; ++u) {
      const float4* wr = (const float4*)(wl + (64 + c0 + u) * 64 + half * 32);
      #pragma unroll
      for (int i8 = 0; i8 < 8; ++i8) {
        float4 ww = wr[i8];
        acc[i8 * 4 + 0] += ww.x * v[u];
        acc[i8 * 4 + 1] += ww.y * v[u];
        acc[i8 * 4 + 2] += ww.z * v[u];
        acc[i8 * 4 + 3] += ww.w * v[u];
      }
    }
  }
  // k = 128..191 : x = feats[:, t]
  const float* xb = xfeats + (long)(n * T_ + t) * CHW_ + p;
  for (int c0 = 0; c0 < 64; c0 += 4) {
    float v[4];
    #pragma unroll
    for (int u = 0; u < 4; ++u) v[u] = xb[(long)(c0 + u) * HW_];
    #pragma unroll
    for (int u = 0; u < 4; ++u) {
      const float4* wr = (const float4*)(wl + (128 + c0 + u) * 64 + half * 32);
      #pragma unroll
      for (int i8 = 0; i8 < 8; ++i8) {
        float4 ww = wr[i8];
        acc[i8 * 4 + 0] += ww.x * v[u];
        acc[i8 * 4 + 1] += ww.y * v[u];
        acc[i8 * 4 + 2] += ww.z * v[u];
        acc[i8 * 4 + 3] += ww.w * v[u];
      }
    }
  }

  float* o = ifp + (long)n * ifs + p;
  #pragma unroll
  for (int i = 0; i < 32; i++) o[(long)(half * 32 + i) * HW_] = acc[i];
}

// 3x3 SAME conv 64->64, fp32. v4:
//   R2 post-mortem: v3's register-array double-buffer spilled to scratch
//   (WRITE_SIZE 8MB->1.29GB) — on this compiler, cross-iteration register
//   arrays are the spill trigger. v2's real bottleneck (VALUBusy 22%) was
//   the 18 scalar VMEM weight loads per cc-step: 36KB/block not L1-resident
//   -> ~200cyc L2 round-trips on the critical path (~1100 cyc/cc ~= 119us).
//   v4 = v2 chassis (flat scalars, single-buffer tile, stage->sync->compute
//   ->sync; VGPR ~52 there, zero scratch) + ONE change: block's weights
//   preloaded to LDS once (64ci x 16co x 9, stride padded to 12 floats ->
//   16B-aligned ds_read_b128, colane bank-starts {0,12,24,4,16,28,8,20}%32
//   = disjoint 4-bank groups, conflict-free). Per cc weights = 4x b128 +
//   2x b32 from LDS; zero VMEM in the main loop.
//   FMA order per output unchanged -> bit-identical.
//   Expected: mildly LDS-bound, ~1250 cyc/cc/CU -> ~40us/dispatch.
// MODE 0: +bias1, leaky_relu.  MODE 1: +bias2 +x residual.
template <int MODE>
__global__ __launch_bounds__(256) void conv3_k(
    const float* __restrict__ in, long ins,       // input planes, n-stride
    const float* __restrict__ Wt,                 // (64,64,3,3)
    const float* __restrict__ bias,
    const float* __restrict__ xfeats, int t,      // residual source (MODE 1)
    float* __restrict__ outf, long outs) {        // fp32 out planes, n-stride
  constexpr int TS = 24;        // padded tile row stride (floats)
  constexpr int CI_STEP = 4;    // ci planes staged per barrier round
  constexpr int WSTR = 12;      // padded per-(co,ci) weight stride (floats)
  __shared__ __align__(16) float tile[CI_STEP][18][TS];      // 6912 B
  __shared__ __align__(16) float wlds[64 * 16 * WSTR];       // 49152 B

  const int tilex = blockIdx.x, tiley = blockIdx.y;
  const int n = blockIdx.z >> 2, cog = blockIdx.z & 3;
  const int tid = threadIdx.x;
  const int colane = tid & 7;        // 0..7
  const int patch  = tid >> 3;       // 0..31
  const int prr = patch >> 2;        // 0..7  (2-row strips)
  const int pcc = patch & 3;         // 0..3  (4-col strips)
  const int co0 = cog * 16 + colane; // thread's channels: co0 and co0+8

  // ---- one-time: preload this block's 16-co weight set into LDS ----
  // global Wt[(cog*16+co16)*576 + ci*9 + j] -> wlds[ci*192 + co16*12 + j]
  for (int i = tid; i < 16 * 64 * 9; i += 256) {
    int co16 = i / 576;
    int rem  = i - co16 * 576;           // ci*9 + j
    int ci   = rem / 9;
    int j    = rem - ci * 9;
    wlds[ci * 192 + co16 * WSTR + j] =
        Wt[((long)(cog * 16 + co16)) * 576 + rem];
  }
  // (first __syncthreads below covers this preload)

  float acc[2][2][4];
  #pragma unroll
  for (int q = 0; q < 2; q++)
    #pragma unroll
    for (int i = 0; i < 2; i++)
      #pragma unroll
      for (int j = 0; j < 4; j++) acc[q][i][j] = 0.f;

  const float* inn = in + (long)n * ins;
  const int gy0 = tiley * 16 - 1, gx0 = tilex * 16 - 1;

  for (int cb = 0; cb < 64; cb += CI_STEP) {
    // ---- stage CI_STEP input planes (18x18 valid, zero-padded edges) ----
    for (int cc = 0; cc < CI_STEP; cc++) {
      const float* ip = inn + (long)(cb + cc) * HW_;
      for (int i = tid; i < 324; i += 256) {
        int r = i / 18, c = i - r * 18;
        int gy = gy0 + r, gx = gx0 + c;
        float v = 0.f;
        if (gy >= 0 && gy < H_ && gx >= 0 && gx < W_) v = ip[gy * W_ + gx];
        tile[cc][r][c] = v;
      }
    }
    __syncthreads();

    for (int cc = 0; cc < CI_STEP; cc++) {
      const int ci = cb + cc;
      // weights from LDS: 2x b128 + 1x b32 per co (conflict-free)
      const float* wrow0 = wlds + ci * 192 + colane * WSTR;
      const float* wrow1 = wrow0 + 8 * WSTR;
      float4 wa0 = *(const float4*)(wrow0);
      float4 wa1 = *(const float4*)(wrow0 + 4);
      float  wa2 = wrow0[8];
      float4 wb0 = *(const float4*)(wrow1);
      float4 wb1 = *(const float4*)(wrow1 + 4);
      float  wb2 = wrow1[8];
      float w0[9], w1[9];
      w0[0] = wa0.x; w0[1] = wa0.y; w0[2] = wa0.z; w0[3] = wa0.w;
      w0[4] = wa1.x; w0[5] = wa1.y; w0[6] = wa1.z; w0[7] = wa1.w;
      w0[8] = wa2;
      w1[0] = wb0.x; w1[1] = wb0.y; w1[2] = wb0.z; w1[3] = wb0.w;
      w1[4] = wb1.x; w1[5] = wb1.y; w1[6] = wb1.z; w1[7] = wb1.w;
      w1[8] = wb2;

      // input registers: 4 rows x 8 cols via 2x ds_read_b128 per row
      float vv[4][8];
      #pragma unroll
      for (int r = 0; r < 4; r++) {
        const float* tp = &tile[cc][prr * 2 + r][pcc * 4];
        float4 a = *reinterpret_cast<const float4*>(tp);
        float4 b = *reinterpret_cast<const float4*>(tp + 4);
        vv[r][0] = a.x; vv[r][1] = a.y; vv[r][2] = a.z; vv[r][3] = a.w;
        vv[r][4] = b.x; vv[r][5] = b.y; vv[r][6] = b.z; vv[r][7] = b.w;
      }

      // 2 co x 2 oy x 4 ox x 9 taps = 288 FMA per ci
      // (per-output order ci -> ky -> kx identical to v1/v2: bit-identical)
      #pragma unroll
      for (int oy = 0; oy < 2; oy++)
        #pragma unroll
        for (int ky = 0; ky < 3; ky++)
          #pragma unroll
          for (int kx = 0; kx < 3; kx++)
            #pragma unroll
            for (int ox = 0; ox < 4; ox++) {
              float x = vv[oy + ky][ox + kx];
              acc[0][oy][ox] += w0[ky * 3 + kx] * x;
              acc[1][oy][ox] += w1[ky * 3 + kx] * x;
            }
    }
    __syncthreads();
  }

  // ---- epilogue: bias (+leaky | +residual), float4 stores ----
  const int py0 = tiley * 16 + prr * 2, px0 = tilex * 16 + pcc * 4;
  #pragma unroll
  for (int q = 0; q < 2; q++) {
    const int co = co0 + q * 8;
    const float bs = bias[co];
    float* ob = outf + (long)n * outs + (long)co * HW_;
    const float* xb = (MODE == 1)
        ? xfeats + (long)(n * T_ + t) * CHW_ + (long)co * HW_ : nullptr;
    #pragma unroll
    for (int oy = 0; oy < 2; oy++) {
      const long p = (long)(py0 + oy) * W_ + px0;
      float4 r;
      r.x = acc[q][oy][0] + bs;
      r.y = acc[q][oy][1] + bs;
      r.z = acc[q][oy][2] + bs;
      r.w = acc[q][oy][3] + bs;
      if (MODE == 0) {
        r.x = (r.x > 0.f) ? r.x : 0.1f * r.x;
        r.y = (r.y > 0.f) ? r.y : 0.1f * r.y;
        r.z = (r.z > 0.f) ? r.z : 0.1f * r.z;
        r.w = (r.w > 0.f) ? r.w : 0.1f * r.w;
      } else {
        float4 xres = *reinterpret_cast<const float4*>(&xb[p]);
        r.x += xres.x; r.y += xres.y; r.z += xres.z; r.w += xres.w;
      }
      *reinterpret_cast<float4*>(&ob[p]) = r;
    }
  }
}

extern "C" void kernel_launch(void* const* d_in, const int* in_sizes, int n_in,
                              void* d_out, int out_size, void* d_ws, size_t ws_size,
                              hipStream_t stream) {
  // Inputs fp32 AND output fp32 (reference returns jnp.float32; the test's
  // "(bf16, ...)" label is a hardcoded string).
  //
  // d_out planes (n,t) are the exact fp32 recurrent state: written at step t,
  // read as y1/y2 at steps t+1/t+2 (feats plane 0 for t<2). Scratch (infeat,
  // h1) -> d_ws if >=16 MiB, else dead feats/d_out planes (restore-per-launch
  // semantics make feats planes reusable once consumed).
  float* fmut = (float*)d_in[0];              // feats (2,16,64,128,128)
  const float* flows = (const float*)d_in[1]; // (2,16,2,128,128)
  const float* Wfc   = (const float*)d_in[2]; // (64,192)
  const float* bfc   = (const float*)d_in[3];
  const float* W1    = (const float*)d_in[4]; // (64,64,3,3)
  const float* b1v   = (const float*)d_in[5];
  const float* W2    = (const float*)d_in[6];
  const float* b2v   = (const float*)d_in[7];
  float* outF = (float*)d_out;                // (2,16,64,128,128) fp32

  const long FS = (long)T_ * CHW_;            // n-stride of feats/out (floats)
  float* ws = (float*)d_ws;
  const bool use_ws = ws_size >= (size_t)4 * CHW_ * sizeof(float);  // 16 MiB

  dim3 g3(8, 8, 8);
  for (int t = 0; t < T_; t++) {
    // ---- state sources (n-stride FS for both feats and out) ----
    const float* y1p = (t >= 1) ? outF + (long)(t - 1) * CHW_ : fmut;
    const float* y2p = (t >= 2) ? outF + (long)(t - 2) * CHW_ : fmut;

    // ---- scratch: infeat and h1 ----
    float *ifp, *h1p;
    long ifs, h1s;
    if (use_ws) {
      ifp = ws;                 ifs = CHW_;   // (N,C,H,W), 8 MiB
      h1p = ws + 2 * CHW_;      h1s = CHW_;   // 8 MiB
    } else {
      if (t == 0)      { ifp = outF + (long)14 * CHW_; ifs = FS; }
      else if (t == 1) { ifp = outF + (long)15 * CHW_; ifs = FS; }
      else             { ifp = fmut + (long)(t - 1) * CHW_; ifs = FS; }
      if (t == 0)      { h1p = outF + (long)15 * CHW_; h1s = FS; }
      else             { h1p = fmut; h1s = FS; }   // feats plane 0, dead for t>=1
    }

    warp_fc_k<<<256, 256, 0, stream>>>(
        flows, fmut, y1p, FS, y2p, FS, Wfc, bfc, t - 1, t - 2, t, ifp, ifs);
    conv3_k<0><<<g3, 256, 0, stream>>>(ifp, ifs, W1, b1v, nullptr, 0, h1p, h1s);
    conv3_k<1><<<g3, 256, 0, stream>>>(h1p, h1s, W2, b2v, fmut, t,
                                       outF + (long)t * CHW_, FS);
  }
}

// Round 4
// 3136.767 us; speedup vs baseline: 5.3828x; 1.2504x over previous
//
#include <hip/hip_runtime.h>
#include <hip/hip_bf16.h>

#define DEV __device__ __forceinline__

namespace {
constexpr int T_ = 16;
constexpr int C_ = 64;
constexpr int H_ = 128;
constexpr int W_ = 128;
constexpr int HW_ = H_ * W_;            // 16384
constexpr long CHW_ = (long)C_ * HW_;   // 1,048,576 floats per (n,t) plane
}

struct Bil { int o00, o01, o10, o11; float w00, w01, w10, w11; };

DEV Bil make_bil(float gx, float gy) {
  float x0f = floorf(gx), y0f = floorf(gy);
  float wx = gx - x0f, wy = gy - y0f;
  int x0 = (int)x0f, y0 = (int)y0f;
  int x1 = x0 + 1, y1 = y0 + 1;
  bool vx0 = (x0 >= 0) && (x0 < W_), vx1 = (x1 >= 0) && (x1 < W_);
  bool vy0 = (y0 >= 0) && (y0 < H_), vy1 = (y1 >= 0) && (y1 < H_);
  int cx0 = min(max(x0, 0), W_ - 1), cx1 = min(max(x1, 0), W_ - 1);
  int cy0 = min(max(y0, 0), H_ - 1), cy1 = min(max(y1, 0), H_ - 1);
  Bil b;
  b.o00 = cy0 * W_ + cx0; b.o01 = cy0 * W_ + cx1;
  b.o10 = cy1 * W_ + cx0; b.o11 = cy1 * W_ + cx1;
  b.w00 = (vx0 && vy0) ? (1.f - wx) * (1.f - wy) : 0.f;
  b.w01 = (vx1 && vy0) ? wx * (1.f - wy) : 0.f;
  b.w10 = (vx0 && vy1) ? (1.f - wx) * wy : 0.f;
  b.w11 = (vx1 && vy1) ? wx * wy : 0.f;
  return b;
}

// Kernel 1: flow-warp (a2, a1) + concat x + 1x1 conv (192->64), all fp32.
// v5: R3 analysis: old grid=256 -> 1 block/CU -> 1 wave/SIMD, zero latency
// hiding; plus 1536 broadcast ds_read_b128 of wave-UNIFORM weights/thread.
// Fix: (a) weights read straight from global with wave-uniform indices ->
// compiler emits s_load_dwordx4; v_fmac takes the SGPR operand. No LDS at
// all. (b) co split 32->16/thread (quarters), pixels in 128-px chunks ->
// grid 1024 x 128 threads = 8 waves/CU.
// Per-acc k-order (c0 ascending, u ascending) unchanged -> bit-identical.
__global__ __launch_bounds__(128) void warp_fc_k(
    const float* __restrict__ flows,    // (N,T,2,HW)
    const float* __restrict__ xfeats,   // pristine feats base (x_t source)
    const float* __restrict__ y1p, long y1s,   // y1 planes, n-stride (floats)
    const float* __restrict__ y2p, long y2s,   // y2 planes
    const float* __restrict__ Wfc, const float* __restrict__ bfc,
    int f1t, int f2t, int t,
    float* __restrict__ ifp, long ifs) {       // infeat out, n-stride
  const int tid = threadIdx.x;               // 0..127
  const int bx  = blockIdx.x;                // 0..1023
  const int n       = bx >> 9;               // 0..1
  const int quarter = (bx >> 7) & 3;         // co-quarter 0..3
  const int p       = ((bx & 127) << 7) + tid;   // 0..16383
  const int py = p >> 7, px = p & (W_ - 1);

  float f1x = 0.f, f1y = 0.f;
  if (f1t >= 0) {
    const float* fp = flows + (long)((n * T_ + f1t) * 2) * HW_;
    f1x = fp[p];
    f1y = fp[HW_ + p];
  }
  Bil b1 = make_bil((float)px + f1x, (float)py + f1y);

  float f2cx = f1x, f2cy = f1y;   // warp of zero field is zero
  if (f2t >= 0) {
    const float* f2p = flows + (long)((n * T_ + f2t) * 2) * HW_;
    f2cx += b1.w00 * f2p[b1.o00] + b1.w01 * f2p[b1.o01] +
            b1.w10 * f2p[b1.o10] + b1.w11 * f2p[b1.o11];
    const float* f2q = f2p + HW_;
    f2cy += b1.w00 * f2q[b1.o00] + b1.w01 * f2q[b1.o01] +
            b1.w10 * f2q[b1.o10] + b1.w11 * f2q[b1.o11];
  }
  Bil b2 = make_bil((float)px + f2cx, (float)py + f2cy);

  float acc[16];
  #pragma unroll
  for (int i = 0; i < 16; i++) acc[i] = bfc[quarter * 16 + i];

  // this quarter's weight rows: Wfc[(quarter*16+co)*192 + k], k-contiguous
  const float* wq = Wfc + (long)(quarter * 16) * 192;

  // k = 0..63 : a2 = warp(y2, f2c)
  const float* y2b = y2p + (long)n * y2s;
  for (int c0 = 0; c0 < 64; c0 += 4) {
    float v[4];
    #pragma unroll
    for (int u = 0; u < 4; ++u) {
      const float* pl = y2b + (long)(c0 + u) * HW_;
      v[u] = b2.w00 * pl[b2.o00] + b2.w01 * pl[b2.o01] +
             b2.w10 * pl[b2.o10] + b2.w11 * pl[b2.o11];
    }
    #pragma unroll
    for (int co = 0; co < 16; ++co) {
      // uniform address -> s_load_dwordx4 (16B-aligned: 192*4B row stride)
      float4 w = *(const float4*)(wq + (long)co * 192 + c0);
      acc[co] += w.x * v[0];
      acc[co] += w.y * v[1];
      acc[co] += w.z * v[2];
      acc[co] += w.w * v[3];
    }
  }
  // k = 64..127 : a1 = warp(y1, f1)
  const float* y1b = y1p + (long)n * y1s;
  for (int c0 = 0; c0 < 64; c0 += 4) {
    float v[4];
    #pragma unroll
    for (int u = 0; u < 4; ++u) {
      const float* pl = y1b + (long)(c0 + u) * HW_;
      v[u] = b1.w00 * pl[b1.o00] + b1.w01 * pl[b1.o01] +
             b1.w10 * pl[b1.o10] + b1.w11 * pl[b1.o11];
    }
    #pragma unroll
    for (int co = 0; co < 16; ++co) {
      float4 w = *(const float4*)(wq + (long)co * 192 + 64 + c0);
      acc[co] += w.x * v[0];
      acc[co] += w.y * v[1];
      acc[co] += w.z * v[2];
      acc[co] += w.w * v[3];
    }
  }
  // k = 128..191 : x = feats[:, t]
  const float* xb = xfeats + (long)(n * T_ + t) * CHW_ + p;
  for (int c0 = 0; c0 < 64; c0 += 4) {
    float v[4];
    #pragma unroll
    for (int u = 0; u < 4; ++u) v[u] = xb[(long)(c0 + u) * HW_];
    #pragma unroll
    for (int co = 0; co < 16; ++co) {
      float4 w = *(const float4*)(wq + (long)co * 192 + 128 + c0);
      acc[co] += w.x * v[0];
      acc[co] += w.y * v[1];
      acc[co] += w.z * v[2];
      acc[co] += w.w * v[3];
    }
  }

  float* o = ifp + (long)n * ifs + p;
  #pragma unroll
  for (int i = 0; i < 16; i++) o[(long)(quarter * 16 + i) * HW_] = acc[i];
}

// 3x3 SAME conv 64->64, fp32. v5:
//   R3 post-mortem: v4 (86.7us) had both pipes <40% -> stall-bound: single-
//   buffered tile serializes {stage -> VMEM wait -> barrier -> compute ->
//   barrier} with only 2 waves/SIMD of cover. v3's register-dbuf spilled;
//   the safe form is LDS tile double-buffer (+6.9KB only): issue next
//   round's 6 global loads at round start (T14 issue-early), compute 4 ci
//   from buf A, ds_write into buf B, ONE barrier per round. Per-thread
//   pipelined state = 6 scalars (no spill trigger). Weights stay in LDS
//   (WSTR=12, conflict-free b128). FMA order unchanged -> bit-identical.
// MODE 0: +bias1, leaky_relu.  MODE 1: +bias2 +x residual.
template <int MODE>
__global__ __launch_bounds__(256) void conv3_k(
    const float* __restrict__ in, long ins,       // input planes, n-stride
    const float* __restrict__ Wt,                 // (64,64,3,3)
    const float* __restrict__ bias,
    const float* __restrict__ xfeats, int t,      // residual source (MODE 1)
    float* __restrict__ outf, long outs) {        // fp32 out planes, n-stride
  constexpr int TS = 24;         // padded tile row stride (floats)
  constexpr int PL = 18 * TS;    // 432 floats per ci plane
  constexpr int CI_STEP = 4;     // ci planes per round
  constexpr int HB = CI_STEP * PL;   // 1728 floats per buffer
  constexpr int WSTR = 12;       // padded per-(co,ci) weight stride (floats)
  __shared__ __align__(16) float tile[2 * HB];         // 13824 B
  __shared__ __align__(16) float wlds[64 * 16 * WSTR]; // 49152 B (total 63KB)

  const int tilex = blockIdx.x, tiley = blockIdx.y;
  const int n = blockIdx.z >> 2, cog = blockIdx.z & 3;
  const int tid = threadIdx.x;
  const int colane = tid & 7;        // 0..7
  const int patch  = tid >> 3;       // 0..31
  const int prr = patch >> 2;        // 0..7  (2-row strips)
  const int pcc = patch & 3;         // 0..3  (4-col strips)
  const int co0 = cog * 16 + colane; // thread's channels: co0 and co0+8

  const float* inn = in + (long)n * ins;
  const int gy0 = tiley * 16 - 1, gx0 = tilex * 16 - 1;

  // ---- one-time: preload this block's 16-co weight set into LDS ----
  // global Wt[(cog*16+co16)*576 + ci*9 + j] -> wlds[ci*192 + co16*12 + j]
  for (int i = tid; i < 16 * 64 * 9; i += 256) {
    int co16 = i / 576;
    int rem  = i - co16 * 576;           // ci*9 + j
    int ci   = rem / 9;
    int j    = rem - ci * 9;
    wlds[ci * 192 + co16 * WSTR + j] =
        Wt[((long)(cog * 16 + co16)) * 576 + rem];
  }

  // ---- staging slots: 4 planes x 18x18 = 1296 elems over 256 threads ----
  int soff[6]; int slds[6]; bool sval[6]; bool sact[6];
  #pragma unroll
  for (int s = 0; s < 6; ++s) {
    int idx = tid + s * 256;
    sact[s] = idx < 1296;
    int idc = sact[s] ? idx : 0;
    int cc = idc / 324; int rem = idc - cc * 324;
    int r = rem / 18;   int c = rem - r * 18;
    int gy = gy0 + r, gx = gx0 + c;
    bool inb = (gy >= 0) && (gy < H_) && (gx >= 0) && (gx < W_);
    sval[s] = sact[s] && inb;
    soff[s] = cc * HW_ + (inb ? (gy * W_ + gx) : 0);
    slds[s] = cc * PL + r * TS + c;
  }

  float acc[2][2][4];
  #pragma unroll
  for (int q = 0; q < 2; q++)
    #pragma unroll
    for (int i = 0; i < 2; i++)
      #pragma unroll
      for (int j = 0; j < 4; j++) acc[q][i][j] = 0.f;

  // ---- prologue: stage round 0 directly into buffer 0 ----
  #pragma unroll
  for (int s = 0; s < 6; ++s)
    if (sact[s]) tile[slds[s]] = sval[s] ? inn[soff[s]] : 0.f;
  __syncthreads();   // covers weight preload + round-0 stage

  for (int rnd = 0; rnd < 16; ++rnd) {
    const int buf = rnd & 1;
    const bool more = rnd < 15;

    // issue next round's global loads FIRST: latency hides under compute
    float sreg[6];
    if (more) {
      const float* nb = inn + (long)(rnd + 1) * CI_STEP * HW_;
      #pragma unroll
      for (int s = 0; s < 6; ++s) sreg[s] = sval[s] ? nb[soff[s]] : 0.f;
    }

    const float* tb = tile + buf * HB;
    #pragma unroll
    for (int cc = 0; cc < CI_STEP; cc++) {
      const int ci = rnd * CI_STEP + cc;
      // weights from LDS: 2x b128 + 1x b32 per co (conflict-free)
      const float* wrow0 = wlds + ci * 192 + colane * WSTR;
      const float* wrow1 = wrow0 + 8 * WSTR;
      float4 wa0 = *(const float4*)(wrow0);
      float4 wa1 = *(const float4*)(wrow0 + 4);
      float  wa2 = wrow0[8];
      float4 wb0 = *(const float4*)(wrow1);
      float4 wb1 = *(const float4*)(wrow1 + 4);
      float  wb2 = wrow1[8];
      float w0[9], w1[9];
      w0[0] = wa0.x; w0[1] = wa0.y; w0[2] = wa0.z; w0[3] = wa0.w;
      w0[4] = wa1.x; w0[5] = wa1.y; w0[6] = wa1.z; w0[7] = wa1.w;
      w0[8] = wa2;
      w1[0] = wb0.x; w1[1] = wb0.y; w1[2] = wb0.z; w1[3] = wb0.w;
      w1[4] = wb1.x; w1[5] = wb1.y; w1[6] = wb1.z; w1[7] = wb1.w;
      w1[8] = wb2;

      // input registers: 4 rows x 8 cols via 2x ds_read_b128 per row
      float vv[4][8];
      #pragma unroll
      for (int r = 0; r < 4; r++) {
        const float* tp = tb + cc * PL + (prr * 2 + r) * TS + pcc * 4;
        float4 a = *reinterpret_cast<const float4*>(tp);
        float4 b = *reinterpret_cast<const float4*>(tp + 4);
        vv[r][0] = a.x; vv[r][1] = a.y; vv[r][2] = a.z; vv[r][3] = a.w;
        vv[r][4] = b.x; vv[r][5] = b.y; vv[r][6] = b.z; vv[r][7] = b.w;
      }

      // 2 co x 2 oy x 4 ox x 9 taps = 288 FMA per ci
      // (per-output order ci -> ky -> kx identical to v1/v2/v4)
      #pragma unroll
      for (int oy = 0; oy < 2; oy++)
        #pragma unroll
        for (int ky = 0; ky < 3; ky++)
          #pragma unroll
          for (int kx = 0; kx < 3; kx++)
            #pragma unroll
            for (int ox = 0; ox < 4; ox++) {
              float x = vv[oy + ky][ox + kx];
              acc[0][oy][ox] += w0[ky * 3 + kx] * x;
              acc[1][oy][ox] += w1[ky * 3 + kx] * x;
            }
    }

    // write next round into the other buffer (its readers finished at the
    // barrier ending round rnd-1), then one barrier per round
    if (more) {
      float* db = tile + (1 - buf) * HB;
      #pragma unroll
      for (int s = 0; s < 6; ++s) if (sact[s]) db[slds[s]] = sreg[s];
    }
    __syncthreads();
  }

  // ---- epilogue: bias (+leaky | +residual), float4 stores ----
  const int py0 = tiley * 16 + prr * 2, px0 = tilex * 16 + pcc * 4;
  #pragma unroll
  for (int q = 0; q < 2; q++) {
    const int co = co0 + q * 8;
    const float bs = bias[co];
    float* ob = outf + (long)n * outs + (long)co * HW_;
    const float* xb = (MODE == 1)
        ? xfeats + (long)(n * T_ + t) * CHW_ + (long)co * HW_ : nullptr;
    #pragma unroll
    for (int oy = 0; oy < 2; oy++) {
      const long p = (long)(py0 + oy) * W_ + px0;
      float4 r;
      r.x = acc[q][oy][0] + bs;
      r.y = acc[q][oy][1] + bs;
      r.z = acc[q][oy][2] + bs;
      r.w = acc[q][oy][3] + bs;
      if (MODE == 0) {
        r.x = (r.x > 0.f) ? r.x : 0.1f * r.x;
        r.y = (r.y > 0.f) ? r.y : 0.1f * r.y;
        r.z = (r.z > 0.f) ? r.z : 0.1f * r.z;
        r.w = (r.w > 0.f) ? r.w : 0.1f * r.w;
      } else {
        float4 xres = *reinterpret_cast<const float4*>(&xb[p]);
        r.x += xres.x; r.y += xres.y; r.z += xres.z; r.w += xres.w;
      }
      *reinterpret_cast<float4*>(&ob[p]) = r;
    }
  }
}

extern "C" void kernel_launch(void* const* d_in, const int* in_sizes, int n_in,
                              void* d_out, int out_size, void* d_ws, size_t ws_size,
                              hipStream_t stream) {
  // Inputs fp32 AND output fp32 (reference returns jnp.float32; the test's
  // "(bf16, ...)" label is a hardcoded string).
  //
  // d_out planes (n,t) are the exact fp32 recurrent state: written at step t,
  // read as y1/y2 at steps t+1/t+2 (feats plane 0 for t<2). Scratch (infeat,
  // h1) -> d_ws if >=16 MiB, else dead feats/d_out planes (restore-per-launch
  // semantics make feats planes reusable once consumed).
  float* fmut = (float*)d_in[0];              // feats (2,16,64,128,128)
  const float* flows = (const float*)d_in[1]; // (2,16,2,128,128)
  const float* Wfc   = (const float*)d_in[2]; // (64,192)
  const float* bfc   = (const float*)d_in[3];
  const float* W1    = (const float*)d_in[4]; // (64,64,3,3)
  const float* b1v   = (const float*)d_in[5];
  const float* W2    = (const float*)d_in[6];
  const float* b2v   = (const float*)d_in[7];
  float* outF = (float*)d_out;                // (2,16,64,128,128) fp32

  const long FS = (long)T_ * CHW_;            // n-stride of feats/out (floats)
  float* ws = (float*)d_ws;
  const bool use_ws = ws_size >= (size_t)4 * CHW_ * sizeof(float);  // 16 MiB

  dim3 g3(8, 8, 8);
  for (int t = 0; t < T_; t++) {
    // ---- state sources (n-stride FS for both feats and out) ----
    const float* y1p = (t >= 1) ? outF + (long)(t - 1) * CHW_ : fmut;
    const float* y2p = (t >= 2) ? outF + (long)(t - 2) * CHW_ : fmut;

    // ---- scratch: infeat and h1 ----
    float *ifp, *h1p;
    long ifs, h1s;
    if (use_ws) {
      ifp = ws;                 ifs = CHW_;   // (N,C,H,W), 8 MiB
      h1p = ws + 2 * CHW_;      h1s = CHW_;   // 8 MiB
    } else {
      if (t == 0)      { ifp = outF + (long)14 * CHW_; ifs = FS; }
      else if (t == 1) { ifp = outF + (long)15 * CHW_; ifs = FS; }
      else             { ifp = fmut + (long)(t - 1) * CHW_; ifs = FS; }
      if (t == 0)      { h1p = outF + (long)15 * CHW_; h1s = FS; }
      else             { h1p = fmut; h1s = FS; }   // feats plane 0, dead for t>=1
    }

    warp_fc_k<<<1024, 128, 0, stream>>>(
        flows, fmut, y1p, FS, y2p, FS, Wfc, bfc, t - 1, t - 2, t, ifp, ifs);
    conv3_k<0><<<g3, 256, 0, stream>>>(ifp, ifs, W1, b1v, nullptr, 0, h1p, h1s);
    conv3_k<1><<<g3, 256, 0, stream>>>(h1p, h1s, W2, b2v, fmut, t,
                                       outF + (long)t * CHW_, FS);
  }
}